// Round 7
// baseline (18154.520 us; speedup 1.0000x reference)
//
#include <hip/hip_runtime.h>

// Problem constants
#define TT 512
#define BB 256
#define II 128
#define HH 256
#define CC 10

typedef __attribute__((ext_vector_type(8))) _Float16 f16x8;
typedef __attribute__((ext_vector_type(4))) _Float16 f16x4;
typedef __attribute__((ext_vector_type(4))) float    f32x4;

__device__ __forceinline__ float fsig(float x){ return 1.0f/(1.0f+__expf(-x)); }
__device__ __forceinline__ float ftanh(float x){ return 2.0f/(1.0f+__expf(-2.0f*x)) - 1.0f; }

// ---- R10 sync design ------------------------------------------------------
// HW facts established this session:
//   (R7)  plain store -> sc0 load IS promptly visible within an XCD's L2.
//   (R8/R9) sc0 LOADS do NOT promptly observe global_atomic_add results --
//          only an RMW observes an RMW. Load-polling an atomic counter
//          burns ~16 spins before a fallback RMW sees the value (-1.8us/step).
//   (R7 residual ~1.7us/step) theory: 16 arrive-RMWs + 30-50 poll-RMWs per
//          counter line per step serialize at the L2 atomic unit; poller
//          RMWs queue AHEAD of the arrivals they wait for.
// => Steady-state sync must be STORE->LOAD only. Per group: a 64B "stamp
//    line" (8-slot ring, slot t&7); wave gj plain-stores t+1 into dword gj
//    after draining h. Waiters lane-parallel sc0-load the 16 dwords and
//    ballot-check all >= expected ('>=' is lead-safe: ring values are
//    monotone +8 per reuse). ZERO RMWs on the critical path. Atomic
//    counters remain ONLY as a capped fallback probe (hang-proof) and are
//    fed by fire-and-forget arrives off the critical path.

// returning RMW at local L2 (sc0 = return old) — R7-proven observer
__device__ __forceinline__ unsigned rmw_ctr_l2(unsigned* p){
  unsigned v, z = 0u;
  asm volatile("global_atomic_add %0, %1, %2, off sc0\n\ts_waitcnt vmcnt(0)"
               : "=v"(v) : "v"(p), "v"(z) : "memory");
  return v;
}
// agent-scope RMW (IF$ coherence point) — baseline-proven observer
__device__ __forceinline__ unsigned rmw_ctr_agent(unsigned* p){
  return __hip_atomic_fetch_add(p, 0u, __ATOMIC_RELAXED, __HIP_MEMORY_SCOPE_AGENT);
}
// Fire-and-forget arrive (+1). Off critical path; feeds the fallback probe.
template<bool FAST>
__device__ __forceinline__ void arrive1(unsigned* p){
  if constexpr(FAST){
    unsigned one = 1u;
    asm volatile("global_atomic_add %0, %1, off" :: "v"(p), "v"(one) : "memory");
  } else {
    (void)__hip_atomic_fetch_add(p, 1u, __ATOMIC_RELAXED, __HIP_MEMORY_SCOPE_AGENT);
  }
}
// Stamp post: plain store (FAST, lands in local L2) / write-through (slow).
template<bool FAST>
__device__ __forceinline__ void store_stamp(unsigned* p, unsigned val){
  if constexpr(FAST)
    asm volatile("global_store_dword %0, %1, off" :: "v"(p), "v"(val) : "memory");
  else
    asm volatile("global_store_dword %0, %1, off sc0 sc1" :: "v"(p), "v"(val) : "memory");
}
// Group wait: lanes 0-15 load the 16 stamp dwords (one 64B line, one RT),
// ballot-check all >= expect. Capped fallback to a proven RMW observer on
// the shadow counter guarantees forward progress even if store->load
// visibility ever stalls (never observed on the data path, but cheap).
template<bool FAST>
__device__ __forceinline__ void wait_group(const unsigned* line, unsigned expect,
                                           unsigned* ctr_fb, unsigned tgt_fb){
  const int lane = threadIdx.x & 63;
  const unsigned* p = line + (lane & 15);
  int spins = 0;
  for(;;){
    unsigned v;
    if constexpr(FAST)
      asm volatile("global_load_dword %0, %1, off sc0\n\ts_waitcnt vmcnt(0)"
                   : "=v"(v) : "v"(p) : "memory");
    else
      asm volatile("global_load_dword %0, %1, off sc0 sc1\n\ts_waitcnt vmcnt(0)"
                   : "=v"(v) : "v"(p) : "memory");
    bool ok = (lane >= 16) || (v >= expect);
    if(__ballot(ok) == ~0ull) break;
    if(++spins >= 256){                          // hang-proof fallback probe
      spins = 0;
      unsigned c = 0;
      if(lane == 0) c = FAST ? rmw_ctr_l2(ctr_fb) : rmw_ctr_agent(ctr_fb);
      c = __builtin_amdgcn_readfirstlane(c);
      if(c >= tgt_fb) break;
    }
    __builtin_amdgcn_s_sleep(1);
  }
  asm volatile("" ::: "memory");   // fence subsequent loads below the wait
}
// Publish h. FAST: plain store -> lands in local L2 (consumers bypass L1).
// slow: write-through to IF$ (sc0 sc1) — proven visibility.
template<bool FAST>
__device__ __forceinline__ void store_h16(_Float16* p, _Float16 vv){
  unsigned b32 = (unsigned)__builtin_bit_cast(unsigned short, vv);
  if constexpr(FAST)
    asm volatile("global_store_short %0, %1, off" :: "v"(p), "v"(b32) : "memory");
  else
    asm volatile("global_store_short %0, %1, off sc0 sc1" :: "v"(p), "v"(b32) : "memory");
}
// Ring loads (addresses reused every 4 steps -> must bypass CU L1).
// FAST: sc0 only (read local L2). slow: sc0 sc1 (read IF$).
template<bool FAST>
__device__ __forceinline__ f16x8 load_ring(const _Float16* p){
  f16x8 r;
  if constexpr(FAST)
    asm volatile("global_load_dwordx4 %0, %1, off sc0" : "=v"(r) : "v"(p) : "memory");
  else
    asm volatile("global_load_dwordx4 %0, %1, off sc0 sc1" : "=v"(r) : "v"(p) : "memory");
  return r;
}
// Pin a loaded fragment: value becomes asm-defined -> compiler cannot
// rematerialize the load inside the loop (the R2/R3 failure mode).
#define PIN(x) asm volatile("" : "+v"(x))

// One WAVE owns: 16 samples (group gb) x 16 units (gj) x ALL 4 gates.
// 4 independent MFMA chains; all 4 gate values for a cell end up in one lane
// (D: row(sample)=quad*4+r, col(unit)=l15) -> elementwise is wave-local.
// Weights fp16, VGPR-resident (pinned). Cross-wave h exchange via L2/IF$;
// group sync via stamp lines (store->load), zero barriers, zero hot RMWs.
template<int KXT, bool IS_L1, bool FAST>
__device__ __forceinline__ void run_wave(
    const _Float16* __restrict__ xin,   // L0: xc [B][T][I] ; L1: h0 [T][B][H]
    const _Float16* __restrict__ Wh,    // fp16 [4H][H]
    const _Float16* __restrict__ Wx,    // fp16 [4H][KXT*32]
    const float* __restrict__ b_ih, const float* __restrict__ b_hh,
    const int* __restrict__ lengths,
    _Float16* __restrict__ hbuf,        // L0: h0 full [T][B][H]; L1: ring [4][B][H]
    float* __restrict__ hT,
    unsigned* cown, unsigned* cprod,    // shadow counters (fallback only)
    unsigned* sown, const unsigned* sprod,  // stamp bases: [8 slots][16 waves]
    int gb, int gj)
{
  constexpr int KXV = KXT*32;
  const int lane = threadIdx.x & 63;
  const int quad = lane >> 4;
  const int l15  = lane & 15;
  const int koff = quad << 3;          // k = quad*8 + j in a 32-wide k-tile
  const int b0   = gb << 4;
  const int u    = (gj << 4) + l15;    // this lane's unit (B col / D col)

  // Stationary weight fragments: B[k][n] = W[g*H+u][k]; pinned in VGPRs.
  f16x8 wh[4][8], wx[4][KXT];
  float bias[4];
#pragma unroll
  for(int g=0; g<4; ++g){
    const int row = g*HH + u;
#pragma unroll
    for(int kt=0; kt<8; ++kt){
      wh[g][kt] = *(const f16x8*)(Wh + (size_t)row*HH + kt*32 + koff);
      PIN(wh[g][kt]);
    }
#pragma unroll
    for(int kt=0; kt<KXT; ++kt){
      wx[g][kt] = *(const f16x8*)(Wx + (size_t)row*KXV + kt*32 + koff);
      PIN(wx[g][kt]);
    }
    bias[g] = b_ih[row] + b_hh[row];
  }

  // Each lane owns 4 cells: samples b0+quad*4+r, unit u. fp32 state in regs.
  int sb[4], len[4]; float cs[4], hs[4];
#pragma unroll
  for(int r=0; r<4; ++r){
    sb[r]  = b0 + (quad<<2) + r;
    len[r] = lengths[sb[r]];
    cs[r] = 0.f; hs[r] = 0.f;
  }

  f16x8 axn[KXT];
  if(!IS_L1){
    const _Float16* xp = xin + ((size_t)(b0+l15)*TT + 0)*KXV + koff;
#pragma unroll
    for(int kt=0; kt<KXT; ++kt) axn[kt] = *(const f16x8*)(xp + kt*32);
  }

  for(int t=0; t<TT; ++t){
    // ---- x-part input fragments
    f16x8 ax[KXT];
    if(IS_L1){
      // wait: L0 group done step t  (stamp value t+1, slot t&7)
      wait_group<FAST>(sprod + (t&7)*16, (unsigned)(t+1),
                       cprod, 16u*(unsigned)(t+1));
      const _Float16* xp = xin + ((size_t)t*BB + b0 + l15)*HH + koff;
      // fresh addresses each t -> plain cached load sees producer's L2 data
#pragma unroll
      for(int kt=0; kt<KXT; ++kt) ax[kt] = *(const f16x8*)(xp + kt*32);
    } else {
#pragma unroll
      for(int kt=0; kt<KXT; ++kt) ax[kt] = axn[kt];
    }

    // ---- wait own group peers (h[t-1] complete), then issue h loads
    if(t > 0){
      // stamp value t at slot (t-1)&7
      wait_group<FAST>(sown + ((t-1)&7)*16, (unsigned)t,
                       cown, 16u*(unsigned)t);
    }
    f16x8 ah[8];
    if(t > 0){
      if(IS_L1){
        const _Float16* hp = hbuf + (((size_t)((t-1)&3))*BB + b0 + l15)*HH + koff;
#pragma unroll
        for(int kt=0; kt<8; ++kt) ah[kt] = load_ring<FAST>(hp + kt*32);
      } else {
        const _Float16* hp = hbuf + ((size_t)(t-1)*BB + b0 + l15)*HH + koff;
#pragma unroll
        for(int kt=0; kt<8; ++kt) ah[kt] = *(const f16x8*)(hp + kt*32);
      }
    }

    // ---- x-MFMAs run under the h-load latency
    f32x4 acc[4];
#pragma unroll
    for(int g=0; g<4; ++g) acc[g] = (f32x4){bias[g],bias[g],bias[g],bias[g]};
#pragma unroll
    for(int kt=0; kt<KXT; ++kt)
#pragma unroll
      for(int g=0; g<4; ++g)
        acc[g] = __builtin_amdgcn_mfma_f32_16x16x32_f16(ax[kt], wx[g][kt], acc[g], 0,0,0);

    if(t > 0){
      if(IS_L1){
        // asm loads: compiler doesn't know a wait is needed -> tie regs to it
        asm volatile("s_waitcnt vmcnt(0)"
          : "+v"(ah[0]),"+v"(ah[1]),"+v"(ah[2]),"+v"(ah[3]),
            "+v"(ah[4]),"+v"(ah[5]),"+v"(ah[6]),"+v"(ah[7]) :: "memory");
      }
#pragma unroll
      for(int kt=0; kt<8; ++kt)
#pragma unroll
        for(int g=0; g<4; ++g)
          acc[g] = __builtin_amdgcn_mfma_f32_16x16x32_f16(ah[kt], wh[g][kt], acc[g], 0,0,0);
    }

    // ---- elementwise cell update (all gates in-lane, no exchange)
#pragma unroll
    for(int r=0; r<4; ++r){
      float iv = fsig (acc[0][r]);
      float fv = fsig (acc[1][r]);
      float gv = ftanh(acc[2][r]);
      float ov = fsig (acc[3][r]);
      float cn = fv*cs[r] + iv*gv;
      float hn = ov*ftanh(cn);
      if(t < len[r]){ cs[r] = cn; hs[r] = hn; }   // freeze past length
      _Float16* hp = IS_L1
        ? hbuf + (((size_t)(t&3))*BB + sb[r])*HH + u
        : hbuf + ((size_t)t*BB + sb[r])*HH + u;
      store_h16<FAST>(hp, (_Float16)hs[r]);
      if(IS_L1 && t == TT-1) hT[(size_t)sb[r]*HH + u] = hs[r];
    }

    // ---- drain own stores, then post stamp (store->load signal) + arrive
    asm volatile("s_waitcnt vmcnt(0)" ::: "memory");
    if(lane == 0){
      store_stamp<FAST>(sown + (t&7)*16 + gj, (unsigned)(t+1));
      arrive1<FAST>(cown);              // feeds fallback probe only
    }

    // ---- prefetch next x AFTER the drain so it isn't waited on; lands
    //      during the next wait window
    if(!IS_L1 && t+1 < TT){
      const _Float16* xp = xin + ((size_t)(b0+l15)*TT + (t+1))*KXV + koff;
#pragma unroll
      for(int kt=0; kt<KXT; ++kt) axn[kt] = *(const f16x8*)(xp + kt*32);
    }
  }
}

// 512 single-wave WGs: layer = blk>>8, gb = blk&15, gj = (blk>>4)&15.
// blk%8 == gb%8 -> a group's 16 waves AND its partner-layer group share an
// XCD under round-robin dispatch. Startup handshake VERIFIES this (via
// HW_REG_XCC_ID) and selects the L2-scope fast path only when true;
// otherwise the proven agent-scope path runs — correctness never depends
// on dispatch placement (G16), only speed does.
__global__ __launch_bounds__(64, 1)
void lstm_fused(const _Float16* __restrict__ xc,
                const _Float16* __restrict__ Wh0, const _Float16* __restrict__ Wx0,
                const _Float16* __restrict__ Wh1, const _Float16* __restrict__ Wx1,
                const float* __restrict__ b_ih0, const float* __restrict__ b_hh0,
                const float* __restrict__ b_ih1, const float* __restrict__ b_hh1,
                const int* __restrict__ lens,
                _Float16* __restrict__ h0seq, _Float16* __restrict__ h1ring,
                float* __restrict__ hT, unsigned* __restrict__ ctr,
                unsigned* __restrict__ stamps)
{
  const int blk   = blockIdx.x;
  const int layer = blk >> 8;
  const int gb    = blk & 15;
  const int gj    = (blk >> 4) & 15;
  const int lane  = threadIdx.x & 63;
  unsigned* c0    = ctr + gb*32;          // 128B-padded shadow counters
  unsigned* c1    = ctr + (16+gb)*32;
  unsigned* s0    = stamps + (gb*8)*16;       // [8 slots][16 waves] dwords
  unsigned* s1    = stamps + ((16+gb)*8)*16;
  unsigned* xcds  = ctr + 1024;           // [512] published XCC ids (ws+4K)
  unsigned* cinit = ctr + 1536;           // startup barrier counter (ws+6K)

  // ---- one-time colocation handshake (agent scope, proven primitives) ----
  unsigned myx;
  asm volatile("s_getreg_b32 %0, hwreg(HW_REG_XCC_ID)" : "=s"(myx));
  if(lane == 0){
    asm volatile("global_store_dword %0, %1, off sc0 sc1" :: "v"(xcds + blk), "v"(myx) : "memory");
    asm volatile("s_waitcnt vmcnt(0)" ::: "memory");
    (void)__hip_atomic_fetch_add(cinit, 1u, __ATOMIC_RELAXED, __HIP_MEMORY_SCOPE_AGENT);
  }
  unsigned iv = 0;
  if(lane == 0){
    iv = __hip_atomic_fetch_add(cinit, 0u, __ATOMIC_RELAXED, __HIP_MEMORY_SCOPE_AGENT);
    while(iv < 512u){ __builtin_amdgcn_s_sleep(8);
      iv = __hip_atomic_fetch_add(cinit, 0u, __ATOMIC_RELAXED, __HIP_MEMORY_SCOPE_AGENT); }
  }
  (void)__builtin_amdgcn_readfirstlane(iv);
  asm volatile("" ::: "memory");
  // lanes 0..31 each check one of the 32 waves of this group-pair
  unsigned pv = myx;
  if(lane < 32){
    const unsigned* pp = xcds + ((lane < 16) ? (gb + 16*lane)
                                             : (256 + gb + 16*(lane-16)));
    asm volatile("global_load_dword %0, %1, off sc0 sc1\n\ts_waitcnt vmcnt(0)"
                 : "=v"(pv) : "v"(pp) : "memory");
  }
  const bool fast = (__ballot(pv == myx) == ~0ull);

  if(layer == 0){
    if(fast) run_wave<4,false,true >(xc, Wh0, Wx0, b_ih0, b_hh0, lens, h0seq,
                                     nullptr, c0, nullptr, s0, nullptr, gb, gj);
    else     run_wave<4,false,false>(xc, Wh0, Wx0, b_ih0, b_hh0, lens, h0seq,
                                     nullptr, c0, nullptr, s0, nullptr, gb, gj);
  } else {
    if(fast) run_wave<8,true ,true >(h0seq, Wh1, Wx1, b_ih1, b_hh1, lens, h1ring,
                                     hT, c1, c0, s1, s0, gb, gj);
    else     run_wave<8,true ,false>(h0seq, Wh1, Wx1, b_ih1, b_hh1, lens, h1ring,
                                     hT, c1, c0, s1, s0, gb, gj);
  }
}

// fp32 -> fp16 elementwise convert (vectorized x4)
__global__ __launch_bounds__(256)
void cvt4(const float* __restrict__ in, _Float16* __restrict__ out, int n4)
{
  int i = blockIdx.x*256 + threadIdx.x;
  if(i < n4){
    float4 v = ((const float4*)in)[i];
    f16x4 o;
    o[0]=(_Float16)v.x; o[1]=(_Float16)v.y; o[2]=(_Float16)v.z; o[3]=(_Float16)v.w;
    ((f16x4*)out)[i] = o;
  }
}

// logits = hT @ W_fc^T + b_fc ; softmax over 10 classes. One wave per sample.
__global__ __launch_bounds__(64)
void fc_softmax(const float* __restrict__ hT,
                const float* __restrict__ W_fc,
                const float* __restrict__ b_fc,
                float* __restrict__ out)
{
  const int b = blockIdx.x;
  const int lane = threadIdx.x;
  float p[CC];
#pragma unroll
  for (int c = 0; c < CC; ++c) p[c] = 0.f;
  const float* hb = hT + b * HH;
  for (int k = lane; k < HH; k += 64){
    float hv = hb[k];
#pragma unroll
    for (int c = 0; c < CC; ++c) p[c] += hv * W_fc[c * HH + k];
  }
#pragma unroll
  for (int c = 0; c < CC; ++c){
#pragma unroll
    for (int off = 32; off > 0; off >>= 1) p[c] += __shfl_down(p[c], off);
  }
  if (lane == 0){
    float m = -1e30f;
#pragma unroll
    for (int c = 0; c < CC; ++c){ p[c] += b_fc[c]; m = fmaxf(m, p[c]); }
    float ssum = 0.f;
#pragma unroll
    for (int c = 0; c < CC; ++c){ p[c] = __expf(p[c] - m); ssum += p[c]; }
    float inv = 1.0f / ssum;
#pragma unroll
    for (int c = 0; c < CC; ++c) out[b * CC + c] = p[c] * inv;
  }
}

extern "C" void kernel_launch(void* const* d_in, const int* in_sizes, int n_in,
                              void* d_out, int out_size, void* d_ws, size_t ws_size,
                              hipStream_t stream) {
  const float* x      = (const float*)d_in[0];   // [B][T][I]
  const int*   lens   = (const int*)  d_in[1];   // [B]
  const float* W_fc   = (const float*)d_in[2];   // [C][H]
  const float* b_fc   = (const float*)d_in[3];   // [C]
  const float* W_ih0  = (const float*)d_in[4];   // [4H][I]
  const float* W_hh0  = (const float*)d_in[5];   // [4H][H]
  const float* b_ih0  = (const float*)d_in[6];
  const float* b_hh0  = (const float*)d_in[7];
  const float* W_ih1  = (const float*)d_in[8];   // [4H][H]
  const float* W_hh1  = (const float*)d_in[9];
  const float* b_ih1  = (const float*)d_in[10];
  const float* b_hh1  = (const float*)d_in[11];
  float* out = (float*)d_out;

  char* ws = (char*)d_ws;
  // ws layout (bytes):
  //   [0, 4K)          shadow counters (2 layers x 16 groups x 128B)
  //   [4K, 6K)         xcds[512] (handshake)
  //   [6K, 8K)         cinit barrier counter
  //   [8K, +256K)      hT fp32
  //   [270336 ..)      fp16 weights: Wh0(512K) Wx0(256K) Wh1(512K) Wx1(512K)
  //   [2105344 ..)     xc fp16 [B][T][I]  (32 MB)
  //   [35659776 ..)    h0seq fp16 [T][B][H] (64 MB)
  //   [102768640 ..)   h1 ring fp16 [4][B][H] (512 KB)
  //   [103292928 ..)   stamps: 2 layers x 16 groups x 8 slots x 64B = 16 KB
  unsigned* ctr    = (unsigned*)ws;
  float*    hT     = (float*)(ws + 8192);
  _Float16* Wh0c   = (_Float16*)(ws + 270336);
  _Float16* Wx0c   = (_Float16*)(ws + 794624);
  _Float16* Wh1c   = (_Float16*)(ws + 1056768);
  _Float16* Wx1c   = (_Float16*)(ws + 1581056);
  _Float16* xc     = (_Float16*)(ws + 2105344);
  _Float16* h0     = (_Float16*)(ws + 35659776);
  _Float16* h1r    = (_Float16*)(ws + 102768640);
  unsigned* stamps = (unsigned*)(ws + 103292928);

  hipMemsetAsync(ws, 0, 8192, stream);                 // counters + handshake
  hipMemsetAsync(ws + 103292928, 0, 16384, stream);    // stamp rings

  // prep: fp32 -> fp16 (weights + x), removes all in-loop conversion work
  cvt4<<<dim3((BB*TT*II/4 + 255)/256), dim3(256), 0, stream>>>(x,     xc,   BB*TT*II/4);
  cvt4<<<dim3((4*HH*HH/4  + 255)/256), dim3(256), 0, stream>>>(W_hh0, Wh0c, 4*HH*HH/4);
  cvt4<<<dim3((4*HH*II/4  + 255)/256), dim3(256), 0, stream>>>(W_ih0, Wx0c, 4*HH*II/4);
  cvt4<<<dim3((4*HH*HH/4  + 255)/256), dim3(256), 0, stream>>>(W_hh1, Wh1c, 4*HH*HH/4);
  cvt4<<<dim3((4*HH*HH/4  + 255)/256), dim3(256), 0, stream>>>(W_ih1, Wx1c, 4*HH*HH/4);

  lstm_fused<<<dim3(512), dim3(64), 0, stream>>>(
      xc, Wh0c, Wx0c, Wh1c, Wx1c, b_ih0, b_hh0, b_ih1, b_hh1, lens,
      h0, h1r, hT, ctr, stamps);

  fc_softmax<<<dim3(BB), dim3(64), 0, stream>>>(hT, W_fc, b_fc, out);
}

// Round 8
// 1650.170 us; speedup vs baseline: 11.0016x; 11.0016x over previous
//
#include <hip/hip_runtime.h>

// Problem constants
#define TT 512
#define BB 256
#define II 128
#define HH 256
#define CC 10

typedef __attribute__((ext_vector_type(8))) _Float16 f16x8;
typedef __attribute__((ext_vector_type(4))) _Float16 f16x4;
typedef __attribute__((ext_vector_type(4))) float    f32x4;

__device__ __forceinline__ float fsig(float x){ return 1.0f/(1.0f+__expf(-x)); }
__device__ __forceinline__ float ftanh(float x){ return 2.0f/(1.0f+__expf(-2.0f*x)) - 1.0f; }

// ---- R11 sync design ------------------------------------------------------
// HW facts (this session):
//  * RMW observes RMW and plain-store updates promptly (baseline/R7 data path).
//  * Spinning LOADS (sc0 or sc0sc1-on-L2) do NOT promptly observe remote
//    updates (R9: atomics invisible; R10: plain stores invisible, 35us/wait).
//  * IF$ (sc1) store->load works but is slower than RMW polling (R4).
// => Polling must be RMW. R7's residual ~2us/step attributed to same-line RMW
//    contention: 16 pollers + 16 arrivers serialize on ONE L2 atomic slot,
//    pollers queueing AHEAD of the arrivals they await.
// R11: single-writer/single-poller lines. Arrive = returning fetch_add(+1) on
// the shared group counter (16 pipelined adds/step, no spin). The LAST
// arriver (old == 16*(t+1)-1) fan-out-stores t+1 to per-wave private release
// lines (one lane-parallel store). Each wave RMW-polls ONLY its private line
// (1 poller, 1 writer -> zero queueing). Fallback probe on the shared counter
// every 16 spins keeps it hang-proof (worst case ~R7 speed).

// returning RMW read (data=0) at local L2 (sc0 = return old) — R7-proven
__device__ __forceinline__ unsigned rmw_ctr_l2(unsigned* p){
  unsigned v, z = 0u;
  asm volatile("global_atomic_add %0, %1, %2, off sc0\n\ts_waitcnt vmcnt(0)"
               : "=v"(v) : "v"(p), "v"(z) : "memory");
  return v;
}
__device__ __forceinline__ unsigned rmw_ctr_agent(unsigned* p){
  return __hip_atomic_fetch_add(p, 0u, __ATOMIC_RELAXED, __HIP_MEMORY_SCOPE_AGENT);
}
// returning fetch_add(+1)
template<bool FAST>
__device__ __forceinline__ unsigned fadd1_ret(unsigned* p){
  if constexpr(FAST){
    unsigned v, one = 1u;
    asm volatile("global_atomic_add %0, %1, %2, off sc0\n\ts_waitcnt vmcnt(0)"
                 : "=v"(v) : "v"(p), "v"(one) : "memory");
    return v;
  } else {
    return __hip_atomic_fetch_add(p, 1u, __ATOMIC_RELAXED, __HIP_MEMORY_SCOPE_AGENT);
  }
}
// release store: plain (FAST, write-through to local L2; the poller's RMW
// reads L2 -> sees it) / sc0 sc1 (slow, IF$ write-through)
template<bool FAST>
__device__ __forceinline__ void store_rel(unsigned* p, unsigned val){
  if constexpr(FAST)
    asm volatile("global_store_dword %0, %1, off" :: "v"(p), "v"(val) : "memory");
  else
    asm volatile("global_store_dword %0, %1, off sc0 sc1" :: "v"(p), "v"(val) : "memory");
}
// Private-line wait: lane0 RMW-polls its OWN line (single poller, no queue).
// Fallback: every 16 spins probe the shared arrive counter (proven observer).
template<bool FAST>
__device__ __forceinline__ unsigned poll_rel(unsigned* line, unsigned tgt,
                                             unsigned* ctr_fb, unsigned cnt_fb){
  unsigned v = 0;
  if((threadIdx.x & 63) == 0){
    v = FAST ? rmw_ctr_l2(line) : rmw_ctr_agent(line);
    int spins = 0;
    while(v < tgt){
      if(++spins >= 16){
        spins = 0;
        unsigned c = FAST ? rmw_ctr_l2(ctr_fb) : rmw_ctr_agent(ctr_fb);
        if(c >= cnt_fb){ v = tgt; break; }       // released per shared counter
      }
      __builtin_amdgcn_s_sleep(FAST ? 1 : 2);
      v = FAST ? rmw_ctr_l2(line) : rmw_ctr_agent(line);
    }
  }
  unsigned u = __builtin_amdgcn_readfirstlane(v);
  asm volatile("" ::: "memory");   // fence subsequent loads below the wait
  return u;
}
// Arrive + conditional fan-out release. relA always (own group, 16 lines);
// relB optional (partner-layer group, 16 lines). Lane-parallel stores.
template<bool FAST>
__device__ __forceinline__ void arrive_release(unsigned* ctr, unsigned tp1,
                                               unsigned* relA, unsigned* relB){
  const int lane = threadIdx.x & 63;
  unsigned old = 0;
  if(lane == 0) old = fadd1_ret<FAST>(ctr);
  old = __builtin_amdgcn_readfirstlane(old);
  if(old == 16u*tp1 - 1u){                       // I am the last arriver
    unsigned* q = nullptr;
    if(lane < 16)                 q = relA + lane*16;
    else if(relB && lane < 32)    q = relB + (lane-16)*16;
    if(q) store_rel<FAST>(q, tp1);
  }
}
// Publish h. FAST: plain store -> local L2. slow: write-through IF$.
template<bool FAST>
__device__ __forceinline__ void store_h16(_Float16* p, _Float16 vv){
  unsigned b32 = (unsigned)__builtin_bit_cast(unsigned short, vv);
  if constexpr(FAST)
    asm volatile("global_store_short %0, %1, off" :: "v"(p), "v"(b32) : "memory");
  else
    asm volatile("global_store_short %0, %1, off sc0 sc1" :: "v"(p), "v"(b32) : "memory");
}
// Ring loads (addresses reused every 4 steps -> must bypass CU L1).
template<bool FAST>
__device__ __forceinline__ f16x8 load_ring(const _Float16* p){
  f16x8 r;
  if constexpr(FAST)
    asm volatile("global_load_dwordx4 %0, %1, off sc0" : "=v"(r) : "v"(p) : "memory");
  else
    asm volatile("global_load_dwordx4 %0, %1, off sc0 sc1" : "=v"(r) : "v"(p) : "memory");
  return r;
}
#define PIN(x) asm volatile("" : "+v"(x))

// One WAVE owns: 16 samples (group gb) x 16 units (gj) x ALL 4 gates.
// Structure identical to the proven R7 kernel; only the sync primitives
// changed (private release lines instead of shared-line RMW polling).
template<int KXT, bool IS_L1, bool FAST>
__device__ __forceinline__ void run_wave(
    const _Float16* __restrict__ xin,   // L0: xc [B][T][I] ; L1: h0 [T][B][H]
    const _Float16* __restrict__ Wh,    // fp16 [4H][H]
    const _Float16* __restrict__ Wx,    // fp16 [4H][KXT*32]
    const float* __restrict__ b_ih, const float* __restrict__ b_hh,
    const int* __restrict__ lengths,
    _Float16* __restrict__ hbuf,        // L0: h0 full [T][B][H]; L1: ring [4][B][H]
    float* __restrict__ hT,
    unsigned* cown, unsigned* cprod,    // shared arrive counters (+fallback)
    unsigned* relOwn,                   // own group's 16 release lines (base)
    unsigned* relAux,                   // L0: partner L1 group's lines (release);
                                        // L1: prod release lines (poll)
    int gb, int gj)
{
  constexpr int KXV = KXT*32;
  const int lane = threadIdx.x & 63;
  const int quad = lane >> 4;
  const int l15  = lane & 15;
  const int koff = quad << 3;          // k = quad*8 + j in a 32-wide k-tile
  const int b0   = gb << 4;
  const int u    = (gj << 4) + l15;    // this lane's unit (B col / D col)

  // Stationary weight fragments: B[k][n] = W[g*H+u][k]; pinned in VGPRs.
  f16x8 wh[4][8], wx[4][KXT];
  float bias[4];
#pragma unroll
  for(int g=0; g<4; ++g){
    const int row = g*HH + u;
#pragma unroll
    for(int kt=0; kt<8; ++kt){
      wh[g][kt] = *(const f16x8*)(Wh + (size_t)row*HH + kt*32 + koff);
      PIN(wh[g][kt]);
    }
#pragma unroll
    for(int kt=0; kt<KXT; ++kt){
      wx[g][kt] = *(const f16x8*)(Wx + (size_t)row*KXV + kt*32 + koff);
      PIN(wx[g][kt]);
    }
    bias[g] = b_ih[row] + b_hh[row];
  }

  // Each lane owns 4 cells: samples b0+quad*4+r, unit u. fp32 state in regs.
  int sb[4], len[4]; float cs[4], hs[4];
#pragma unroll
  for(int r=0; r<4; ++r){
    sb[r]  = b0 + (quad<<2) + r;
    len[r] = lengths[sb[r]];
    cs[r] = 0.f; hs[r] = 0.f;
  }

  unsigned lastp = 0, lasto = 0;   // monotone caches (skip poll when ahead)
  unsigned* myOwnLine  = relOwn + gj*16;
  unsigned* myProdLine = IS_L1 ? (relAux + gj*16) : nullptr;

  f16x8 axn[KXT];
  if(!IS_L1){
    const _Float16* xp = xin + ((size_t)(b0+l15)*TT + 0)*KXV + koff;
#pragma unroll
    for(int kt=0; kt<KXT; ++kt) axn[kt] = *(const f16x8*)(xp + kt*32);
  }

  for(int t=0; t<TT; ++t){
    // ---- x-part input fragments
    f16x8 ax[KXT];
    if(IS_L1){
      const unsigned tgtp = (unsigned)(t+1);              // L0 done step t
      if(lastp < tgtp)
        lastp = poll_rel<FAST>(myProdLine, tgtp, cprod, 16u*tgtp);
      const _Float16* xp = xin + ((size_t)t*BB + b0 + l15)*HH + koff;
#pragma unroll
      for(int kt=0; kt<KXT; ++kt) ax[kt] = *(const f16x8*)(xp + kt*32);
    } else {
#pragma unroll
      for(int kt=0; kt<KXT; ++kt) ax[kt] = axn[kt];
    }

    // ---- wait own group peers (h[t-1] complete), then issue h loads
    if(t > 0){
      const unsigned tgto = (unsigned)t;
      if(lasto < tgto)
        lasto = poll_rel<FAST>(myOwnLine, tgto, cown, 16u*tgto);
    }
    f16x8 ah[8];
    if(t > 0){
      if(IS_L1){
        const _Float16* hp = hbuf + (((size_t)((t-1)&3))*BB + b0 + l15)*HH + koff;
#pragma unroll
        for(int kt=0; kt<8; ++kt) ah[kt] = load_ring<FAST>(hp + kt*32);
      } else {
        const _Float16* hp = hbuf + ((size_t)(t-1)*BB + b0 + l15)*HH + koff;
#pragma unroll
        for(int kt=0; kt<8; ++kt) ah[kt] = *(const f16x8*)(hp + kt*32);
      }
    }

    // ---- x-MFMAs run under the h-load latency
    f32x4 acc[4];
#pragma unroll
    for(int g=0; g<4; ++g) acc[g] = (f32x4){bias[g],bias[g],bias[g],bias[g]};
#pragma unroll
    for(int kt=0; kt<KXT; ++kt)
#pragma unroll
      for(int g=0; g<4; ++g)
        acc[g] = __builtin_amdgcn_mfma_f32_16x16x32_f16(ax[kt], wx[g][kt], acc[g], 0,0,0);

    if(t > 0){
      if(IS_L1){
        // asm loads: compiler doesn't know a wait is needed -> tie regs to it
        asm volatile("s_waitcnt vmcnt(0)"
          : "+v"(ah[0]),"+v"(ah[1]),"+v"(ah[2]),"+v"(ah[3]),
            "+v"(ah[4]),"+v"(ah[5]),"+v"(ah[6]),"+v"(ah[7]) :: "memory");
      }
#pragma unroll
      for(int kt=0; kt<8; ++kt)
#pragma unroll
        for(int g=0; g<4; ++g)
          acc[g] = __builtin_amdgcn_mfma_f32_16x16x32_f16(ah[kt], wh[g][kt], acc[g], 0,0,0);
    }

    // ---- elementwise cell update (all gates in-lane, no exchange)
#pragma unroll
    for(int r=0; r<4; ++r){
      float iv = fsig (acc[0][r]);
      float fv = fsig (acc[1][r]);
      float gv = ftanh(acc[2][r]);
      float ov = fsig (acc[3][r]);
      float cn = fv*cs[r] + iv*gv;
      float hn = ov*ftanh(cn);
      if(t < len[r]){ cs[r] = cn; hs[r] = hn; }   // freeze past length
      _Float16* hp = IS_L1
        ? hbuf + (((size_t)(t&3))*BB + sb[r])*HH + u
        : hbuf + ((size_t)t*BB + sb[r])*HH + u;
      store_h16<FAST>(hp, (_Float16)hs[r]);
      if(IS_L1 && t == TT-1) hT[(size_t)sb[r]*HH + u] = hs[r];
    }

    // ---- drain own stores, arrive; last arriver fan-out releases
    asm volatile("s_waitcnt vmcnt(0)" ::: "memory");
    arrive_release<FAST>(cown, (unsigned)(t+1), relOwn,
                         IS_L1 ? nullptr : relAux);

    // ---- prefetch next x AFTER the drain (lands during next wait window)
    if(!IS_L1 && t+1 < TT){
      const _Float16* xp = xin + ((size_t)(b0+l15)*TT + (t+1))*KXV + koff;
#pragma unroll
      for(int kt=0; kt<KXT; ++kt) axn[kt] = *(const f16x8*)(xp + kt*32);
    }
  }
}

// 512 single-wave WGs: layer = blk>>8, gb = blk&15, gj = (blk>>4)&15.
// blk%8 == gb%8 -> a group's 16 waves AND its partner-layer group share an
// XCD under round-robin dispatch. Startup handshake VERIFIES this and
// selects the L2-scope fast path; otherwise the agent-scope path runs —
// correctness never depends on placement (G16), only speed.
__global__ __launch_bounds__(64, 1)
void lstm_fused(const _Float16* __restrict__ xc,
                const _Float16* __restrict__ Wh0, const _Float16* __restrict__ Wx0,
                const _Float16* __restrict__ Wh1, const _Float16* __restrict__ Wx1,
                const float* __restrict__ b_ih0, const float* __restrict__ b_hh0,
                const float* __restrict__ b_ih1, const float* __restrict__ b_hh1,
                const int* __restrict__ lens,
                _Float16* __restrict__ h0seq, _Float16* __restrict__ h1ring,
                float* __restrict__ hT, unsigned* __restrict__ ctr,
                unsigned* __restrict__ rel)
{
  const int blk   = blockIdx.x;
  const int layer = blk >> 8;
  const int gb    = blk & 15;
  const int gj    = (blk >> 4) & 15;
  const int lane  = threadIdx.x & 63;
  unsigned* c0    = ctr + gb*32;          // 128B-padded shared counters
  unsigned* c1    = ctr + (16+gb)*32;
  // release-line arrays: [16 lines x 16 dwords(64B)] per group
  unsigned* rel0  = rel + (gb      )*256; // L0 own lines
  unsigned* rel1  = rel + (16 + gb )*256; // L1 own lines
  unsigned* relp  = rel + (32 + gb )*256; // L0->L1 prod lines
  unsigned* xcds  = ctr + 1024;           // [512] published XCC ids (ws+4K)
  unsigned* cinit = ctr + 1536;           // startup barrier counter (ws+6K)

  // ---- one-time colocation handshake (agent scope, proven primitives) ----
  unsigned myx;
  asm volatile("s_getreg_b32 %0, hwreg(HW_REG_XCC_ID)" : "=s"(myx));
  if(lane == 0){
    asm volatile("global_store_dword %0, %1, off sc0 sc1" :: "v"(xcds + blk), "v"(myx) : "memory");
    asm volatile("s_waitcnt vmcnt(0)" ::: "memory");
    (void)__hip_atomic_fetch_add(cinit, 1u, __ATOMIC_RELAXED, __HIP_MEMORY_SCOPE_AGENT);
  }
  unsigned iv = 0;
  if(lane == 0){
    iv = __hip_atomic_fetch_add(cinit, 0u, __ATOMIC_RELAXED, __HIP_MEMORY_SCOPE_AGENT);
    while(iv < 512u){ __builtin_amdgcn_s_sleep(8);
      iv = __hip_atomic_fetch_add(cinit, 0u, __ATOMIC_RELAXED, __HIP_MEMORY_SCOPE_AGENT); }
  }
  (void)__builtin_amdgcn_readfirstlane(iv);
  asm volatile("" ::: "memory");
  // lanes 0..31 each check one of the 32 waves of this group-pair
  unsigned pv = myx;
  if(lane < 32){
    const unsigned* pp = xcds + ((lane < 16) ? (gb + 16*lane)
                                             : (256 + gb + 16*(lane-16)));
    asm volatile("global_load_dword %0, %1, off sc0 sc1\n\ts_waitcnt vmcnt(0)"
                 : "=v"(pv) : "v"(pp) : "memory");
  }
  const bool fast = (__ballot(pv == myx) == ~0ull);

  if(layer == 0){
    if(fast) run_wave<4,false,true >(xc, Wh0, Wx0, b_ih0, b_hh0, lens, h0seq,
                                     nullptr, c0, nullptr, rel0, relp, gb, gj);
    else     run_wave<4,false,false>(xc, Wh0, Wx0, b_ih0, b_hh0, lens, h0seq,
                                     nullptr, c0, nullptr, rel0, relp, gb, gj);
  } else {
    if(fast) run_wave<8,true ,true >(h0seq, Wh1, Wx1, b_ih1, b_hh1, lens, h1ring,
                                     hT, c1, c0, rel1, relp, gb, gj);
    else     run_wave<8,true ,false>(h0seq, Wh1, Wx1, b_ih1, b_hh1, lens, h1ring,
                                     hT, c1, c0, rel1, relp, gb, gj);
  }
}

// fp32 -> fp16 elementwise convert (vectorized x4)
__global__ __launch_bounds__(256)
void cvt4(const float* __restrict__ in, _Float16* __restrict__ out, int n4)
{
  int i = blockIdx.x*256 + threadIdx.x;
  if(i < n4){
    float4 v = ((const float4*)in)[i];
    f16x4 o;
    o[0]=(_Float16)v.x; o[1]=(_Float16)v.y; o[2]=(_Float16)v.z; o[3]=(_Float16)v.w;
    ((f16x4*)out)[i] = o;
  }
}

// logits = hT @ W_fc^T + b_fc ; softmax over 10 classes. One wave per sample.
__global__ __launch_bounds__(64)
void fc_softmax(const float* __restrict__ hT,
                const float* __restrict__ W_fc,
                const float* __restrict__ b_fc,
                float* __restrict__ out)
{
  const int b = blockIdx.x;
  const int lane = threadIdx.x;
  float p[CC];
#pragma unroll
  for (int c = 0; c < CC; ++c) p[c] = 0.f;
  const float* hb = hT + b * HH;
  for (int k = lane; k < HH; k += 64){
    float hv = hb[k];
#pragma unroll
    for (int c = 0; c < CC; ++c) p[c] += hv * W_fc[c * HH + k];
  }
#pragma unroll
  for (int c = 0; c < CC; ++c){
#pragma unroll
    for (int off = 32; off > 0; off >>= 1) p[c] += __shfl_down(p[c], off);
  }
  if (lane == 0){
    float m = -1e30f;
#pragma unroll
    for (int c = 0; c < CC; ++c){ p[c] += b_fc[c]; m = fmaxf(m, p[c]); }
    float ssum = 0.f;
#pragma unroll
    for (int c = 0; c < CC; ++c){ p[c] = __expf(p[c] - m); ssum += p[c]; }
    float inv = 1.0f / ssum;
#pragma unroll
    for (int c = 0; c < CC; ++c) out[b * CC + c] = p[c] * inv;
  }
}

extern "C" void kernel_launch(void* const* d_in, const int* in_sizes, int n_in,
                              void* d_out, int out_size, void* d_ws, size_t ws_size,
                              hipStream_t stream) {
  const float* x      = (const float*)d_in[0];   // [B][T][I]
  const int*   lens   = (const int*)  d_in[1];   // [B]
  const float* W_fc   = (const float*)d_in[2];   // [C][H]
  const float* b_fc   = (const float*)d_in[3];   // [C]
  const float* W_ih0  = (const float*)d_in[4];   // [4H][I]
  const float* W_hh0  = (const float*)d_in[5];   // [4H][H]
  const float* b_ih0  = (const float*)d_in[6];
  const float* b_hh0  = (const float*)d_in[7];
  const float* W_ih1  = (const float*)d_in[8];   // [4H][H]
  const float* W_hh1  = (const float*)d_in[9];
  const float* b_ih1  = (const float*)d_in[10];
  const float* b_hh1  = (const float*)d_in[11];
  float* out = (float*)d_out;

  char* ws = (char*)d_ws;
  // ws layout (bytes):
  //   [0, 4K)          shared arrive counters (2 layers x 16 groups x 128B)
  //   [4K, 6K)         xcds[512] (handshake)
  //   [6K, 8K)         cinit barrier counter
  //   [8K, +256K)      hT fp32
  //   [270336 ..)      fp16 weights: Wh0(512K) Wx0(256K) Wh1(512K) Wx1(512K)
  //   [2105344 ..)     xc fp16 [B][T][I]  (32 MB)
  //   [35659776 ..)    h0seq fp16 [T][B][H] (64 MB)
  //   [102768640 ..)   h1 ring fp16 [4][B][H] (512 KB)
  //   [103292928 ..)   release lines: 3 arrays x 16 groups x 16 x 64B = 48 KB
  unsigned* ctr    = (unsigned*)ws;
  float*    hT     = (float*)(ws + 8192);
  _Float16* Wh0c   = (_Float16*)(ws + 270336);
  _Float16* Wx0c   = (_Float16*)(ws + 794624);
  _Float16* Wh1c   = (_Float16*)(ws + 1056768);
  _Float16* Wx1c   = (_Float16*)(ws + 1581056);
  _Float16* xc     = (_Float16*)(ws + 2105344);
  _Float16* h0     = (_Float16*)(ws + 35659776);
  _Float16* h1r    = (_Float16*)(ws + 102768640);
  unsigned* rel    = (unsigned*)(ws + 103292928);

  hipMemsetAsync(ws, 0, 8192, stream);                 // counters + handshake
  hipMemsetAsync(ws + 103292928, 0, 49152, stream);    // release lines

  // prep: fp32 -> fp16 (weights + x), removes all in-loop conversion work
  cvt4<<<dim3((BB*TT*II/4 + 255)/256), dim3(256), 0, stream>>>(x,     xc,   BB*TT*II/4);
  cvt4<<<dim3((4*HH*HH/4  + 255)/256), dim3(256), 0, stream>>>(W_hh0, Wh0c, 4*HH*HH/4);
  cvt4<<<dim3((4*HH*II/4  + 255)/256), dim3(256), 0, stream>>>(W_ih0, Wx0c, 4*HH*II/4);
  cvt4<<<dim3((4*HH*HH/4  + 255)/256), dim3(256), 0, stream>>>(W_hh1, Wh1c, 4*HH*HH/4);
  cvt4<<<dim3((4*HH*HH/4  + 255)/256), dim3(256), 0, stream>>>(W_ih1, Wx1c, 4*HH*HH/4);

  lstm_fused<<<dim3(512), dim3(64), 0, stream>>>(
      xc, Wh0c, Wx0c, Wh1c, Wx1c, b_ih0, b_hh0, b_ih1, b_hh1, lens,
      h0, h1r, hT, ctr, rel);

  fc_softmax<<<dim3(BB), dim3(64), 0, stream>>>(hT, W_fc, b_fc, out);
}